// Round 10
// baseline (292.889 us; speedup 1.0000x reference)
//
#include <hip/hip_runtime.h>
#include <hip/hip_bf16.h>
#include <math.h>

#define NB 4
#define HH 128
#define WW 128
#define CC 128
#define GG 8
#define GCC 16
#define KK 9
#define NHW (NB*HH*WW)   // 65536

typedef __hip_bfloat16 bf16;
typedef __attribute__((ext_vector_type(8))) short short8;
typedef __attribute__((ext_vector_type(4))) float f32x4;

__device__ __forceinline__ float b2f(bf16 v){ return __bfloat162float(v); }
__device__ __forceinline__ bf16 f2b(float v){ return __float2bfloat16(v); }
__device__ __forceinline__ float gelu_f(float v){ return 0.5f*v*(1.f+erff(v*0.70710678118654752f)); }
__device__ __forceinline__ float lo_bf(unsigned u){ union{unsigned i; float f;} c; c.i = u<<16; return c.f; }
__device__ __forceinline__ float hi_bf(unsigned u){ union{unsigned i; float f;} c; c.i = u&0xffff0000u; return c.f; }
__device__ __forceinline__ unsigned pk(float a, float b){
  return ((unsigned)__bfloat16_as_ushort(f2b(b))<<16) | (unsigned)__bfloat16_as_ushort(f2b(a));
}
__device__ __forceinline__ void st_out(bf16* p, float v){ *p = f2b(v); }
__device__ __forceinline__ void st_out(float* p, float v){ *p = v; }
__device__ __forceinline__ void acc8(float* a, uint4 u, float w){
  a[0]+=w*lo_bf(u.x); a[1]+=w*hi_bf(u.x); a[2]+=w*lo_bf(u.y); a[3]+=w*hi_bf(u.y);
  a[4]+=w*lo_bf(u.z); a[5]+=w*hi_bf(u.z); a[6]+=w*lo_bf(u.w); a[7]+=w*hi_bf(u.w);
}

// ---- fused weight prep: 4 transposes + DCN pack, one launch ----
__global__ __launch_bounds__(256) void prep_k(
    const float* __restrict__ inw,  const float* __restrict__ outw,
    const float* __restrict__ fc1w, const float* __restrict__ fc2w,
    const float* __restrict__ offw, const float* __restrict__ offb,
    const float* __restrict__ maskw,const float* __restrict__ maskb,
    bf16* __restrict__ inwt, bf16* __restrict__ outwt,
    bf16* __restrict__ w1t,  bf16* __restrict__ w2t,
    bf16* __restrict__ wsw,  float* __restrict__ cw)
{
  int idx = blockIdx.x*256 + threadIdx.x;
  if (idx < 16384){
    int n = idx>>7, k = idx&127;
    inwt[idx] = f2b(inw[(size_t)k*128 + n]);
  } else if (idx < 32768){
    int i = idx-16384; int n = i>>7, k = i&127;
    outwt[i] = f2b(outw[(size_t)k*128 + n]);
  } else if (idx < 98304){
    int i = idx-32768; int n = i>>7, k = i&127;
    w1t[i] = f2b(fc1w[(size_t)k*512 + n]);
  } else if (idx < 163840){
    int i = idx-98304; int n = i>>9, k = i&511;
    w2t[i] = f2b(fc2w[(size_t)k*128 + n]);
  } else if (idx < 192512){
    int i = idx-163840; int nn = i>>7, k = i&127;
    float v = (nn<144) ? offw[(size_t)k*144+nn] : (nn<216 ? maskw[(size_t)k*72+(nn-144)] : 0.f);
    wsw[i] = f2b(v);
  } else if (idx < 192736){
    int i = idx-192512;
    cw[i] = (i<144) ? offb[i] : (i<216 ? maskb[i-144] : 0.f);
  }
}

// ---- fused LN1 + in_proj: xn = LN(x) (written out), xp = xn @ in_w + in_b ----
// 64 px/block, 1024 blocks. LDS: h0s(64x136 bf16) + wstage(64x136 bf16).
__global__ __launch_bounds__(256) void lnproj_k(const float* __restrict__ X,
    const float* __restrict__ lng, const float* __restrict__ lnb,
    const bf16* __restrict__ inwt, const float* __restrict__ inb,
    bf16* __restrict__ XN, bf16* __restrict__ XP)
{
  __shared__ bf16 h0s[64*136];
  __shared__ bf16 wst[64*136];
  int tid = threadIdx.x;
  int wave = tid>>6, l = tid&63, lo16 = l&15, quad = l>>4;
  int m0 = blockIdx.x*64;
  { // LN1: thread = (px, 32-ch quarter)
    int px = tid>>2, q = tid&3;
    const float* xr = X + (size_t)(m0+px)*128 + q*32;
    float v[32];
    #pragma unroll
    for (int i=0;i<8;i++) *(float4*)(v+i*4) = *(const float4*)(xr+i*4);
    float s=0.f, ss=0.f;
    #pragma unroll
    for (int i=0;i<32;i++){ s += v[i]; ss += v[i]*v[i]; }
    s  += __shfl_xor(s,1,64);  ss += __shfl_xor(ss,1,64);
    s  += __shfl_xor(s,2,64);  ss += __shfl_xor(ss,2,64);
    float mean = s*(1.f/CC), var = ss*(1.f/CC)-mean*mean, rstd = rsqrtf(var+1e-5f);
    const float* gp = lng + q*32; const float* bp = lnb + q*32;
    uint4* dst  = (uint4*)(&h0s[px*136 + q*32]);
    uint4* dstg = (uint4*)(XN + (size_t)(m0+px)*128 + q*32);
    #pragma unroll
    for (int i=0;i<4;i++){
      float4 g0 = *(const float4*)(gp+i*8),  g1 = *(const float4*)(gp+i*8+4);
      float4 c0v = *(const float4*)(bp+i*8), c1v = *(const float4*)(bp+i*8+4);
      float o0 = (v[i*8+0]-mean)*rstd*g0.x + c0v.x;
      float o1 = (v[i*8+1]-mean)*rstd*g0.y + c0v.y;
      float o2 = (v[i*8+2]-mean)*rstd*g0.z + c0v.z;
      float o3 = (v[i*8+3]-mean)*rstd*g0.w + c0v.w;
      float o4 = (v[i*8+4]-mean)*rstd*g1.x + c1v.x;
      float o5 = (v[i*8+5]-mean)*rstd*g1.y + c1v.y;
      float o6 = (v[i*8+6]-mean)*rstd*g1.z + c1v.z;
      float o7 = (v[i*8+7]-mean)*rstd*g1.w + c1v.w;
      uint4 up; up.x = pk(o0,o1); up.y = pk(o2,o3); up.z = pk(o4,o5); up.w = pk(o6,o7);
      dst[i] = up; dstg[i] = up;
    }
  }
  __syncthreads();
  // A-frags: wave owns 16 rows
  short8 a1[4];
  #pragma unroll
  for (int ks=0;ks<4;ks++)
    a1[ks] = *(const short8*)(&h0s[(wave*16+lo16)*136 + ks*32 + quad*8]);
  f32x4 z = {0.f,0.f,0.f,0.f};
  #pragma unroll
  for (int nc=0;nc<2;nc++){
    if (nc) __syncthreads();   // prior wst reads done
    #pragma unroll
    for (int it=0;it<4;it++){  // stage inwt n-rows nc*64..+64 (all 128 k)
      int e = it*2048 + tid*8;
      int nn = e>>7, kk = e&127;
      *(uint4*)(&wst[nn*136 + kk]) = *(const uint4*)(inwt + (size_t)(nc*64+nn)*128 + kk);
    }
    __syncthreads();
    f32x4 acc[4];
    #pragma unroll
    for (int nt=0;nt<4;nt++) acc[nt]=z;
    #pragma unroll
    for (int ks=0;ks<4;ks++)
      #pragma unroll
      for (int nt=0;nt<4;nt++){
        short8 bfr = *(const short8*)(&wst[(nt*16+lo16)*136 + ks*32 + quad*8]);
        acc[nt] = __builtin_amdgcn_mfma_f32_16x16x32_bf16(a1[ks], bfr, acc[nt], 0,0,0);
      }
    #pragma unroll
    for (int nt=0;nt<4;nt++){
      int col = nc*64 + nt*16 + lo16;
      float bb = inb[col];
      #pragma unroll
      for (int r=0;r<4;r++){
        int row = m0 + wave*16 + quad*4 + r;
        XP[(size_t)row*128 + col] = f2b(acc[nt][r] + bb);
      }
    }
  }
}

// -------- depthwise 3x3 conv + LN + GELU: 16 px x 16 ch-groups, no LDS --------
__global__ __launch_bounds__(256) void convln_k(const bf16* __restrict__ XN,
    const float* __restrict__ dwk, const float* __restrict__ dwb,
    const float* __restrict__ gam, const float* __restrict__ bet, bf16* __restrict__ X1)
{
  int tid = threadIdx.x;
  int px = tid>>4, cg = tid&15;
  int ch0 = cg*8;
  int pix = blockIdx.x*16 + px;           // 16 px stay within one row (128%16==0)
  int w = pix & (WW-1), h = (pix>>7)&(HH-1), n = pix>>14;
  float acc[8];
  {
    float4 b0 = *(const float4*)(dwb + ch0), b1 = *(const float4*)(dwb + ch0 + 4);
    acc[0]=b0.x; acc[1]=b0.y; acc[2]=b0.z; acc[3]=b0.w;
    acc[4]=b1.x; acc[5]=b1.y; acc[6]=b1.z; acc[7]=b1.w;
  }
  #pragma unroll
  for (int ky=0;ky<3;ky++){
    int yy = h+ky-1; if ((unsigned)yy>=(unsigned)HH) continue;
    #pragma unroll
    for (int kx=0;kx<3;kx++){
      int xx = w+kx-1; if ((unsigned)xx>=(unsigned)WW) continue;
      uint4 u = *(const uint4*)(XN + ((size_t)((n*HH+yy)*WW+xx))*CC + ch0);
      const float* wp = dwk + (ky*3+kx)*CC + ch0;
      float4 w0 = *(const float4*)wp; float4 w1 = *(const float4*)(wp+4);
      acc[0] += lo_bf(u.x)*w0.x; acc[1] += hi_bf(u.x)*w0.y;
      acc[2] += lo_bf(u.y)*w0.z; acc[3] += hi_bf(u.y)*w0.w;
      acc[4] += lo_bf(u.z)*w1.x; acc[5] += hi_bf(u.z)*w1.y;
      acc[6] += lo_bf(u.w)*w1.z; acc[7] += hi_bf(u.w)*w1.w;
    }
  }
  float s=0.f, ss=0.f;
  #pragma unroll
  for (int i=0;i<8;i++){ s += acc[i]; ss += acc[i]*acc[i]; }
  #pragma unroll
  for (int off=1; off<16; off<<=1){ s += __shfl_xor(s,off,64); ss += __shfl_xor(ss,off,64); }
  float mean=s*(1.f/CC), var=ss*(1.f/CC)-mean*mean, rstd=rsqrtf(var+1e-5f);
  float4 g0 = *(const float4*)(gam + ch0), g1 = *(const float4*)(gam + ch0 + 4);
  float4 be0 = *(const float4*)(bet + ch0), be1 = *(const float4*)(bet + ch0 + 4);
  float gv[8] = {g0.x,g0.y,g0.z,g0.w,g1.x,g1.y,g1.z,g1.w};
  float bv[8] = {be0.x,be0.y,be0.z,be0.w,be1.x,be1.y,be1.z,be1.w};
  float o[8];
  #pragma unroll
  for (int i=0;i<8;i++) o[i] = gelu_f((acc[i]-mean)*rstd*gv[i] + bv[i]);
  uint4 up; up.x = pk(o[0],o[1]); up.y = pk(o[2],o[3]); up.z = pk(o[4],o[5]); up.w = pk(o[6],o[7]);
  *(uint4*)(X1 + (size_t)pix*CC + ch0) = up;
}

// ---- fused DCN: MFMA projection + softmax + branchless bilinear sampling ----
#define OMS 226   // oms row stride (bf16): 113 dwords, odd -> banks spread
__global__ __launch_bounds__(256) void samp_k(const bf16* __restrict__ X1,
    const bf16* __restrict__ XP,
    const bf16* __restrict__ wsw, const float* __restrict__ cw,
    bf16* __restrict__ Y)
{
  __shared__ bf16 oms[32*OMS];   // 14464 B
  int tid = threadIdx.x;
  int pix0 = blockIdx.x*32;      // 32 px within one row segment
  int wave = tid>>6, l = tid&63, lo16 = l&15, quad = l>>4;
  // ---- phase 1: scores(32x224) = x1[pix0:pix0+32] @ wsw^T + cw, MFMA ----
  int nt0 = wave*4;
  int ntn = (wave==3) ? 2 : 4;
  short8 af[2][4];
  #pragma unroll
  for (int mt=0;mt<2;mt++)
    #pragma unroll
    for (int ks=0;ks<4;ks++)
      af[mt][ks] = *(const short8*)(X1 + (size_t)(pix0+mt*16+lo16)*128 + ks*32 + quad*8);
  f32x4 z = {0.f,0.f,0.f,0.f};
  f32x4 acc[2][4];
  #pragma unroll
  for (int mt=0;mt<2;mt++)
    #pragma unroll
    for (int t=0;t<4;t++) acc[mt][t]=z;
  for (int t=0;t<ntn;t++){
    int nt = nt0+t;
    #pragma unroll
    for (int ks=0;ks<4;ks++){
      short8 bfr = *(const short8*)(wsw + (size_t)(nt*16+lo16)*128 + ks*32 + quad*8);
      acc[0][t] = __builtin_amdgcn_mfma_f32_16x16x32_bf16(af[0][ks], bfr, acc[0][t], 0,0,0);
      acc[1][t] = __builtin_amdgcn_mfma_f32_16x16x32_bf16(af[1][ks], bfr, acc[1][t], 0,0,0);
    }
  }
  for (int t=0;t<ntn;t++){
    int col = (nt0+t)*16 + lo16;
    float bb = cw[col];
    #pragma unroll
    for (int mt=0;mt<2;mt++)
      #pragma unroll
      for (int r=0;r<4;r++)
        oms[(mt*16 + quad*4 + r)*OMS + col] = f2b(acc[mt][t][r] + bb);
  }
  __syncthreads();
  // ---- phase 2: softmax, task = (px, group), 32*8 = 256 ----
  {
    int m = tid>>3, g = tid&7;
    int base = m*OMS + 144 + g*9;
    float sc[9]; float mx = -1e30f;
    #pragma unroll
    for (int k=0;k<9;k++){ sc[k] = b2f(oms[base+k]); mx = fmaxf(mx, sc[k]); }
    float sum = 0.f;
    #pragma unroll
    for (int k=0;k<9;k++){ sc[k] = expf(sc[k]-mx); sum += sc[k]; }
    float inv = 1.f/sum;
    #pragma unroll
    for (int k=0;k<9;k++) oms[base+k] = f2b(sc[k]*inv);
  }
  __syncthreads();
  // ---- phase 3: branchless sampling; lane = ch-oct, slot = tid>>4 ----
  int oct = tid&15, sl = tid>>4;
  int g = oct>>1;
  int ch = g*GCC + (oct&1)*8;
  int w0 = pix0 & (WW-1);
  int h  = (pix0>>7) & (HH-1);
  int n  = pix0>>14;
  const bf16* base = XP + (size_t)n*HH*WW*CC + ch;
  for (int it=0; it<2; it++){
    int m = it*16 + sl;
    int wc = w0 + m;
    const bf16* omrow = &oms[m*OMS];
    float a[8] = {0.f,0.f,0.f,0.f,0.f,0.f,0.f,0.f};
    #pragma unroll
    for (int k=0;k<9;k++){
      float offx = b2f(omrow[g*18 + 2*k]);
      float offy = b2f(omrow[g*18 + 2*k + 1]);
      float mk   = b2f(omrow[144 + g*9 + k]);
      float pxf = (float)(wc + (k/3) - 1) + offx;   // x-major grid
      float pyf = (float)(h  + (k%3) - 1) + offy;
      float x0f = floorf(pxf), y0f = floorf(pyf);
      float txf = pxf-x0f,     tyf = pyf-y0f;
      int x0 = (int)x0f, y0 = (int)y0f;
      int x1i = x0+1,    y1i = y0+1;
      float vx0 = ((unsigned)x0 <(unsigned)WW)?1.f:0.f;
      float vx1 = ((unsigned)x1i<(unsigned)WW)?1.f:0.f;
      float vy0 = ((unsigned)y0 <(unsigned)HH)?1.f:0.f;
      float vy1 = ((unsigned)y1i<(unsigned)HH)?1.f:0.f;
      int cx0 = min(max(x0,0),WW-1),  cx1 = min(max(x1i,0),WW-1);
      int cy0 = min(max(y0,0),HH-1),  cy1 = min(max(y1i,0),HH-1);
      float w00=(1.f-tyf)*(1.f-txf)*mk*vy0*vx0, w01=(1.f-tyf)*txf*mk*vy0*vx1;
      float w10=tyf*(1.f-txf)*mk*vy1*vx0,       w11=tyf*txf*mk*vy1*vx1;
      uint4 u00 = *(const uint4*)(base + ((size_t)(cy0*WW+cx0))*CC);
      uint4 u01 = *(const uint4*)(base + ((size_t)(cy0*WW+cx1))*CC);
      uint4 u10 = *(const uint4*)(base + ((size_t)(cy1*WW+cx0))*CC);
      uint4 u11 = *(const uint4*)(base + ((size_t)(cy1*WW+cx1))*CC);
      acc8(a,u00,w00); acc8(a,u01,w01); acc8(a,u10,w10); acc8(a,u11,w11);
    }
    uint4 outp;
    outp.x = pk(a[0],a[1]); outp.y = pk(a[2],a[3]);
    outp.z = pk(a[4],a[5]); outp.w = pk(a[6],a[7]);
    *(uint4*)(Y + (size_t)(pix0+m)*CC + ch) = outp;
  }
}

// ------------- MFMA GEMM: C(Mx128) = A(Mx128 bf16) @ Bt^T + bias (+res) -------------
template<typename OutT, bool RES>
__global__ __launch_bounds__(256) void gemm_mfma(const bf16* __restrict__ A,
    const bf16* __restrict__ Bt, const float* __restrict__ bias,
    const float* __restrict__ res, OutT* __restrict__ C)
{
  int tid = threadIdx.x;
  int wave = tid>>6, l = tid&63, lo16 = l&15, quad = l>>4;
  int m0 = blockIdx.y*256 + wave*64;
  int n0 = blockIdx.x*64;
  short8 bfr[4][4];   // [kstep][ntile]
  #pragma unroll
  for (int ks=0;ks<4;ks++)
    #pragma unroll
    for (int nt=0;nt<4;nt++)
      bfr[ks][nt] = *(const short8*)(Bt + (size_t)(n0+nt*16+lo16)*128 + ks*32 + quad*8);
  f32x4 z = {0.f,0.f,0.f,0.f};
  f32x4 acc[4][4];
  #pragma unroll
  for (int mt=0;mt<4;mt++)
    #pragma unroll
    for (int nt=0;nt<4;nt++) acc[mt][nt]=z;
  #pragma unroll
  for (int ks=0;ks<4;ks++){
    short8 af[4];
    #pragma unroll
    for (int mt=0;mt<4;mt++)
      af[mt] = *(const short8*)(A + (size_t)(m0+mt*16+lo16)*128 + ks*32 + quad*8);
    #pragma unroll
    for (int nt=0;nt<4;nt++)
      #pragma unroll
      for (int mt=0;mt<4;mt++)
        acc[mt][nt] = __builtin_amdgcn_mfma_f32_16x16x32_bf16(af[mt], bfr[ks][nt], acc[mt][nt], 0,0,0);
  }
  #pragma unroll
  for (int mt=0;mt<4;mt++)
    #pragma unroll
    for (int nt=0;nt<4;nt++){
      int col = n0 + nt*16 + lo16;
      float bb = bias[col];
      #pragma unroll
      for (int r=0;r<4;r++){
        int row = m0 + mt*16 + quad*4 + r;
        float v = acc[mt][nt][r] + bb;
        if (RES) v += res[(size_t)row*128 + col];
        st_out(&C[(size_t)row*128 + col], v);
      }
    }
}

// ---- fused MFMA MLP v3: 64 px/block, internal LN2, LDS weights, 3 barriers/chunk ----
__global__ __launch_bounds__(256) void mlp_mfma(const float* __restrict__ X2,
    const float* __restrict__ lng, const float* __restrict__ lnb,
    const bf16* __restrict__ w1t, const float* __restrict__ b1,
    const bf16* __restrict__ w2t, const float* __restrict__ b2,
    float* __restrict__ OUT)
{
  __shared__ __align__(16) char smem[17408 + 17408 + 18432];   // 53248 B
  bf16* h0s = (bf16*)smem;               // 64 x 136
  bf16* ts  = (bf16*)smem;               // 64 x 72 (aliases h0s after a1 loads)
  bf16* w1s = (bf16*)(smem + 17408);     // 64 x 136
  bf16* w2s = (bf16*)(smem + 34816);     // 128 x 72
  int tid = threadIdx.x;
  int wave = tid>>6, l = tid&63, lo16 = l&15, quad = l>>4;
  int m0 = blockIdx.x*64;
  { // LN2: thread = (px, 32-ch quarter)
    int px = tid>>2, q = tid&3;
    const float* xr = X2 + (size_t)(m0+px)*128 + q*32;
    float v[32];
    #pragma unroll
    for (int i=0;i<8;i++) *(float4*)(v+i*4) = *(const float4*)(xr+i*4);
    float s=0.f, ss=0.f;
    #pragma unroll
    for (int i=0;i<32;i++){ s += v[i]; ss += v[i]*v[i]; }
    s  += __shfl_xor(s,1,64);  ss += __shfl_xor(ss,1,64);
    s  += __shfl_xor(s,2,64);  ss += __shfl_xor(ss,2,64);
    float mean = s*(1.f/CC), var = ss*(1.f/CC)-mean*mean, rstd = rsqrtf(var+1e-5f);
    const float* gp = lng + q*32; const float* bp = lnb + q*32;
    uint4* dst = (uint4*)(&h0s[px*136 + q*32]);
    #pragma unroll
    for (int i=0;i<4;i++){
      float4 g0 = *(const float4*)(gp+i*8),  g1 = *(const float4*)(gp+i*8+4);
      float4 c0v = *(const float4*)(bp+i*8), c1v = *(const float4*)(bp+i*8+4);
      float o0 = (v[i*8+0]-mean)*rstd*g0.x + c0v.x;
      float o1 = (v[i*8+1]-mean)*rstd*g0.y + c0v.y;
      float o2 = (v[i*8+2]-mean)*rstd*g0.z + c0v.z;
      float o3 = (v[i*8+3]-mean)*rstd*g0.w + c0v.w;
      float o4 = (v[i*8+4]-mean)*rstd*g1.x + c1v.x;
      float o5 = (v[i*8+5]-mean)*rstd*g1.y + c1v.y;
      float o6 = (v[i*8+6]-mean)*rstd*g1.z + c1v.z;
      float o7 = (v[i*8+7]-mean)*rstd*g1.w + c1v.w;
      uint4 up; up.x = pk(o0,o1); up.y = pk(o2,o3); up.z = pk(o4,o5); up.w = pk(o6,o7);
      dst[i] = up;
    }
  }
  __syncthreads();
  short8 a1[4];   // wave owns 16 rows
  #pragma unroll
  for (int ks=0;ks<4;ks++)
    a1[ks] = *(const short8*)(&h0s[(wave*16+lo16)*136 + ks*32 + quad*8]);
  f32x4 z = {0.f,0.f,0.f,0.f};
  f32x4 acc2[8];
  #pragma unroll
  for (int nt=0;nt<8;nt++) acc2[nt]=z;

  for (int c0=0;c0<512;c0+=64){
    __syncthreads();   // prior GEMM2 (ts/w2s) + prior GEMM1 (w1s) reads done; a1 loads drained
    #pragma unroll
    for (int it=0;it<4;it++){   // stage w1 chunk: 64 n-rows x 128 k
      int e = it*2048 + tid*8;
      int nn = e>>7, kk = e&127;
      *(uint4*)(&w1s[nn*136 + kk]) = *(const uint4*)(w1t + (size_t)(c0+nn)*128 + kk);
    }
    #pragma unroll
    for (int it=0;it<4;it++){   // stage w2 chunk: 128 n-rows x 64 k
      int e = it*2048 + tid*8;
      int nn = e>>6, kk = e&63;
      *(uint4*)(&w2s[nn*72 + kk]) = *(const uint4*)(w2t + (size_t)nn*512 + c0 + kk);
    }
    __syncthreads();
    // GEMM1: t(64x64) = h0 @ w1[:, c0:c0+64]
    f32x4 acc1[4];
    #pragma unroll
    for (int nt=0;nt<4;nt++) acc1[nt]=z;
    #pragma unroll
    for (int ks=0;ks<4;ks++)
      #pragma unroll
      for (int nt=0;nt<4;nt++){
        short8 bfr = *(const short8*)(&w1s[(nt*16+lo16)*136 + ks*32 + quad*8]);
        acc1[nt] = __builtin_amdgcn_mfma_f32_16x16x32_bf16(a1[ks], bfr, acc1[nt], 0,0,0);
      }
    #pragma unroll
    for (int nt=0;nt<4;nt++){
      float bb = b1[c0 + nt*16 + lo16];
      #pragma unroll
      for (int r=0;r<4;r++)
        ts[(wave*16 + quad*4 + r)*72 + nt*16 + lo16] = f2b(gelu_f(acc1[nt][r] + bb));
    }
    __syncthreads();
    // GEMM2: acc2 += t @ w2[c0:c0+64, :]
    #pragma unroll
    for (int ks2=0;ks2<2;ks2++){
      short8 a2 = *(const short8*)(&ts[(wave*16+lo16)*72 + ks2*32 + quad*8]);
      #pragma unroll
      for (int nt2=0;nt2<8;nt2++){
        short8 bfr2 = *(const short8*)(&w2s[(nt2*16+lo16)*72 + ks2*32 + quad*8]);
        acc2[nt2] = __builtin_amdgcn_mfma_f32_16x16x32_bf16(a2, bfr2, acc2[nt2], 0,0,0);
      }
    }
  }
  #pragma unroll
  for (int nt=0;nt<8;nt++){
    int col = nt*16 + lo16;
    float bb = b2[col];
    #pragma unroll
    for (int r=0;r<4;r++){
      int row = m0 + wave*16 + quad*4 + r;
      float v = acc2[nt][r] + bb + X2[(size_t)row*128 + col];
      OUT[(size_t)row*128 + col] = v;
    }
  }
}

extern "C" void kernel_launch(void* const* d_in, const int* in_sizes, int n_in,
                              void* d_out, int out_size, void* d_ws, size_t ws_size,
                              hipStream_t stream)
{
  const float* x    = (const float*)d_in[0];
  const float* ln1g = (const float*)d_in[1];
  const float* ln1b = (const float*)d_in[2];
  const float* inw  = (const float*)d_in[3];
  const float* inb  = (const float*)d_in[4];
  const float* dwk  = (const float*)d_in[5];
  const float* dwb  = (const float*)d_in[6];
  const float* dwlng= (const float*)d_in[7];
  const float* dwlnb= (const float*)d_in[8];
  const float* offw = (const float*)d_in[9];
  const float* offb = (const float*)d_in[10];
  const float* maskw= (const float*)d_in[11];
  const float* maskb= (const float*)d_in[12];
  const float* outw = (const float*)d_in[13];
  const float* outb = (const float*)d_in[14];
  const float* ln2g = (const float*)d_in[15];
  const float* ln2b = (const float*)d_in[16];
  const float* fc1w = (const float*)d_in[17];
  const float* fc1b = (const float*)d_in[18];
  const float* fc2w = (const float*)d_in[19];
  const float* fc2b = (const float*)d_in[20];
  float* out = (float*)d_out;

  bf16* ws = (bf16*)d_ws;
  const size_t S = (size_t)NHW*CC;
  // ws: R0 [0,S): xn->y | R1 [S,2S): xp | R2 [2S,3S): x1 | [3S,..): weights
  bf16* xn = ws;
  bf16* xp = ws + S;
  bf16* x1 = ws + 2*S;
  bf16* y  = xn;
  float* x2 = out;
  bf16* inwt  = ws + 3*S;            // 128*128
  bf16* outwt = inwt + 128*128;      // 128*128
  bf16* w1t   = outwt + 128*128;     // 512*128
  bf16* w2t   = w1t + 512*128;       // 128*512
  bf16* wsw   = w2t + 128*512;       // 224*128
  float* cw   = (float*)(wsw + 224*128);  // 224 f32

  // 0. fused weight prep (one launch)
  prep_k<<<753, 256, 0, stream>>>(inw, outw, fc1w, fc2w, offw, offb, maskw, maskb,
                                  inwt, outwt, w1t, w2t, wsw, cw);
  // 1+2. xn = LN1(x);  xp = xn @ in_w + in_b   [fused LN+MFMA]
  lnproj_k<<<NHW/64, 256, 0, stream>>>(x, ln1g, ln1b, inwt, inb, xn, xp);
  // 3. x1 = gelu(LN(dwconv(xn)))
  convln_k<<<NHW/16, 256, 0, stream>>>(xn, dwk, dwb, dwlng, dwlnb, x1);
  // 4. y = dcn_core(xp, offset(x1), mask(x1))   [branchless sampling]
  samp_k<<<NHW/32, 256, 0, stream>>>(x1, xp, wsw, cw, y);
  // 5. x2 = x + (y @ out_w + out_b)   [MFMA, f32 into d_out]
  gemm_mfma<float,true><<<dim3(2,256), 256, 0, stream>>>(y, outwt, outb, x, x2);
  // 6+7. out = x2 + gelu(LN2(x2) @ fc1 + b1) @ fc2 + b2   [fused, in-place d_out]
  mlp_mfma<<<NHW/64, 256, 0, stream>>>(x2, ln2g, ln2b, w1t, fc1b, w2t, fc2b, out);
}